// Round 5
// baseline (47.624 us; speedup 1.0000x reference)
//
#include <hip/hip_runtime.h>
#include <stdint.h>

#define NF    64
#define DIM0  50000
#define SROWS 100000
#define QPT   4      // queries per thread
#define TPB   256

typedef float  f32x4 __attribute__((ext_vector_type(4)));
typedef uint32_t u32x4 __attribute__((ext_vector_type(4)));

// ---------------------------------------------------------------------------
// Pass 1: closed-form quantize only. Row = 32B (8 u32, 4-bit codes x64).
//   q = clamp(ceil(16*f - 1), 0, 15)  (bit-exact vs jnp.argmin incl. tie->lower;
//   validated rounds 2-3: absmax 2.4e-7)
// feats read is one-shot -> nontemporal; codes write stays cached (query reads it).
// ---------------------------------------------------------------------------
__global__ void quantize_kernel(const float* __restrict__ feats,
                                uint32_t* __restrict__ qcodes) {
    int gid = blockIdx.x * blockDim.x + threadIdx.x;   // word idx = s*8+w (exact grid)
    const f32x4* fr = (const f32x4*)(feats + (size_t)gid * 8);
    f32x4 fA = __builtin_nontemporal_load(fr);
    f32x4 fB = __builtin_nontemporal_load(fr + 1);
    float fv[8] = {fA.x, fA.y, fA.z, fA.w, fB.x, fB.y, fB.z, fB.w};

    uint32_t word = 0u;
#pragma unroll
    for (int j = 0; j < 8; ++j) {
        float x = fmaf(fv[j], 16.0f, -1.0f);   // exact: 16f-1 representable
        int q = (int)ceilf(x);
        q = q < 0 ? 0 : (q > 15 ? 15 : q);
        word |= (uint32_t)q << (4 * j);
    }
    qcodes[gid] = word;
}

// ---------------------------------------------------------------------------
// Pass 2: 4 queries/thread. Per query: 2 gathers of one 32B line each.
//   t_f = W'*(A*B) + X'*A + Y'*B + C_f
//   asum = sum_{f<32} t_f ; bsum = sum_{f>=32} t_f
//   out  = asum * tanh(bsum) * exp(scale) + bias
// Coefs {W',X',Y'} staged as float4 in LDS (1 broadcast b128 per feature,
// amortized over the 4 queries). Ca/Cb = per-half sums of C_f, butterfly-
// reduced once per block by wave 0.
// ---------------------------------------------------------------------------
__global__ __launch_bounds__(TPB) void query_kernel(
        const uint32_t* __restrict__ qcodes,
        const float* __restrict__ values,
        const float* __restrict__ scale,
        const float* __restrict__ bias,
        const int* __restrict__ idx0,
        const int* __restrict__ idx1,
        float* __restrict__ out, int N) {
    __shared__ float4 sco[NF];       // {W', X', Y', 0}
    __shared__ float  sCa, sCb;
    int t = threadIdx.x;
    if (t < NF) {
        float v0 = values[t], v1 = values[NF + t];
        float v2 = values[2 * NF + t], v3 = values[3 * NF + t];
        float W = v0 - v1 - v2 + v3;
        float X = v1 - v3, Y = v2 - v3;
        float Wp = W * (1.0f / 256.0f);
        float Xp = W * (1.0f / 512.0f) + X * (1.0f / 16.0f);
        float Yp = W * (1.0f / 512.0f) + Y * (1.0f / 16.0f);
        sco[t] = make_float4(Wp, Xp, Yp, 0.0f);
        // C_f, reduced within each 32-lane half of wave 0
        float C = W * (1.0f / 1024.0f) + (X + Y) * (1.0f / 32.0f) + v3;
        C += __shfl_xor(C, 1);  C += __shfl_xor(C, 2);  C += __shfl_xor(C, 4);
        C += __shfl_xor(C, 8);  C += __shfl_xor(C, 16);
        if (t == 0)  sCa = C;
        if (t == 32) sCb = C;
    }
    __syncthreads();

    int base = blockIdx.x * (TPB * QPT) + t;

    // ---- phase 1: issue all gathers (independent -> high MLP) ----
    uint32_t aw[QPT][8], bw[QPT][8];
#pragma unroll
    for (int k = 0; k < QPT; ++k) {
        int n = base + k * TPB;
        int m = n < N ? n : N - 1;
        int r0 = __builtin_nontemporal_load(idx0 + m);
        int r1 = DIM0 + __builtin_nontemporal_load(idx1 + m);
        const u32x4* pa = (const u32x4*)(qcodes + (size_t)r0 * 8);
        const u32x4* pb = (const u32x4*)(qcodes + (size_t)r1 * 8);
        u32x4 x0 = pa[0], x1 = pa[1];
        u32x4 y0 = pb[0], y1 = pb[1];
        aw[k][0] = x0.x; aw[k][1] = x0.y; aw[k][2] = x0.z; aw[k][3] = x0.w;
        aw[k][4] = x1.x; aw[k][5] = x1.y; aw[k][6] = x1.z; aw[k][7] = x1.w;
        bw[k][0] = y0.x; bw[k][1] = y0.y; bw[k][2] = y0.z; bw[k][3] = y0.w;
        bw[k][4] = y1.x; bw[k][5] = y1.y; bw[k][6] = y1.z; bw[k][7] = y1.w;
    }

    // ---- phase 2: contraction, coef read hoisted over the 4 queries ----
    float ca[QPT] = {0.f, 0.f, 0.f, 0.f};
    float cb[QPT] = {0.f, 0.f, 0.f, 0.f};
#pragma unroll
    for (int wd = 0; wd < 8; ++wd) {
#pragma unroll
        for (int j = 0; j < 8; ++j) {
            int f = wd * 8 + j;
            float4 co = sco[f];          // broadcast ds_read_b128
#pragma unroll
            for (int k = 0; k < QPT; ++k) {
                float A = (float)((aw[k][wd] >> (4 * j)) & 15u);
                float B = (float)((bw[k][wd] >> (4 * j)) & 15u);
                float h = fmaf(co.x, B, co.y);          // W'*B + X'
                if (wd < 4) ca[k] = fmaf(A, h, fmaf(co.z, B, ca[k]));
                else        cb[k] = fmaf(A, h, fmaf(co.z, B, cb[k]));
            }
        }
    }

    float es = expf(scale[0]);
    float bi = bias[0];
    float Ca = sCa, Cb = sCb;
#pragma unroll
    for (int k = 0; k < QPT; ++k) {
        int n = base + k * TPB;
        if (n < N) {
            float asum = ca[k] + Ca;
            float bsum = cb[k] + Cb;
            __builtin_nontemporal_store(asum * tanhf(bsum) * es + bi, out + n);
        }
    }
}

extern "C" void kernel_launch(void* const* d_in, const int* in_sizes, int n_in,
                              void* d_out, int out_size, void* d_ws, size_t ws_size,
                              hipStream_t stream) {
    const float* values = (const float*)d_in[0];  // [1,4,64]
    const float* feats  = (const float*)d_in[1];  // [100000,64]
    const float* scale  = (const float*)d_in[3];  // [1]
    const float* bias   = (const float*)d_in[4];  // [1]
    const int*   idx0   = (const int*)d_in[5];    // [N]
    const int*   idx1   = (const int*)d_in[6];    // [N]
    float*       out    = (float*)d_out;          // [N] f32

    uint32_t* qcodes = (uint32_t*)d_ws;           // SROWS*32B = 3.2 MB

    int nwords = SROWS * 8;                       // 800000 = 3125 * 256 exact
    quantize_kernel<<<nwords / TPB, TPB, 0, stream>>>(feats, qcodes);

    int N = out_size;
    int qblocks = (N + TPB * QPT - 1) / (TPB * QPT);
    query_kernel<<<qblocks, TPB, 0, stream>>>(
        qcodes, values, scale, bias, idx0, idx1, out, N);
}

// Round 6
// 36.087 us; speedup vs baseline: 1.3197x; 1.3197x over previous
//
#include <hip/hip_runtime.h>
#include <stdint.h>

#define NF    64
#define DIM0  50000
#define SROWS 100000
#define TPB   256
#define COEF_OFF_BYTES (SROWS * 32)   // coef table after 3.2MB of codes

typedef float    f32x4 __attribute__((ext_vector_type(4)));
typedef uint32_t u32x4 __attribute__((ext_vector_type(4)));

// ---------------------------------------------------------------------------
// Pass 1: closed-form quantize (row = 32B, 64 x 4-bit codes) + coef table.
//   q = clamp(ceil(16*f - 1), 0, 15)   (bit-exact vs jnp.argmin, tie->lower;
//   validated rounds 2-5, absmax <= 2.4e-7)
// Block 0, wave 0 additionally derives per-feature coefficients from values:
//   W'=W/256, X'=W/512+X/16, Y'=W/512+Y/16, C=W/1024+(X+Y)/32+V3
//   (W=V0-V1-V2+V3, X=V1-V3, Y=V2-V3), plus the per-half constant sums Ca,Cb.
// ---------------------------------------------------------------------------
__global__ void quantize_kernel(const float* __restrict__ feats,
                                const float* __restrict__ values,
                                uint32_t* __restrict__ qcodes,
                                float* __restrict__ coef) {
    int t = threadIdx.x;
    if (blockIdx.x == 0 && t < NF) {
        float v0 = values[t], v1 = values[NF + t];
        float v2 = values[2 * NF + t], v3 = values[3 * NF + t];
        float W = v0 - v1 - v2 + v3;
        float X = v1 - v3, Y = v2 - v3;
        float Wp = W * (1.0f / 256.0f);
        float Xp = W * (1.0f / 512.0f) + X * (1.0f / 16.0f);
        float Yp = W * (1.0f / 512.0f) + Y * (1.0f / 16.0f);
        float C  = W * (1.0f / 1024.0f) + (X + Y) * (1.0f / 32.0f) + v3;
        ((f32x4*)coef)[t] = (f32x4){Wp, Xp, Yp, C};
        // per-half constant: lanes 0..31 reduce Ca, lanes 32..63 reduce Cb
        float Cs = C;
        Cs += __shfl_xor(Cs, 1);  Cs += __shfl_xor(Cs, 2);
        Cs += __shfl_xor(Cs, 4);  Cs += __shfl_xor(Cs, 8);
        Cs += __shfl_xor(Cs, 16);
        if (t == 0)  coef[NF * 4 + 0] = Cs;
        if (t == 32) coef[NF * 4 + 1] = Cs;
    }

    int gid = blockIdx.x * blockDim.x + t;   // word idx = s*8+w (exact grid)
    const f32x4* fr = (const f32x4*)(feats + (size_t)gid * 8);
    f32x4 fA = __builtin_nontemporal_load(fr);
    f32x4 fB = __builtin_nontemporal_load(fr + 1);
    float fv[8] = {fA.x, fA.y, fA.z, fA.w, fB.x, fB.y, fB.z, fB.w};

    uint32_t word = 0u;
#pragma unroll
    for (int j = 0; j < 8; ++j) {
        float x = fmaf(fv[j], 16.0f, -1.0f);   // exact: 16f-1 representable
        int q = (int)ceilf(x);
        q = q < 0 ? 0 : (q > 15 ? 15 : q);
        word |= (uint32_t)q << (4 * j);
    }
    qcodes[gid] = word;
}

// ---------------------------------------------------------------------------
// Pass 2: 1 query/thread, exactly 2 gathered lines per query (2x 32B rows).
//   per feature: Af,Bf decode (2 bfe + 2 cvt), pf=Af*Bf (exact),
//   cross += pf*W' ; linA += Af*X' ; linB += Bf*Y'   (1 SGPR coef per fma)
//   asum = crossA+linAa+linBa+Ca ; bsum likewise ; out = a*tanh(b)*e^s + bias
// coef[f] has a uniform address -> s_load_dwordx4 (scalar cache), keeping the
// inner loop free of LDS and extra gathers.
// ---------------------------------------------------------------------------
__global__ __launch_bounds__(TPB) void query_kernel(
        const uint32_t* __restrict__ qcodes,
        const f32x4* __restrict__ coef,
        const float* __restrict__ scale,
        const float* __restrict__ bias,
        const int* __restrict__ idx0,
        const int* __restrict__ idx1,
        float* __restrict__ out, int N) {
    int n = blockIdx.x * TPB + threadIdx.x;
    if (n >= N) return;

    int r0 = __builtin_nontemporal_load(idx0 + n);
    int r1 = DIM0 + __builtin_nontemporal_load(idx1 + n);

    const u32x4* pa = (const u32x4*)(qcodes + (size_t)r0 * 8);
    const u32x4* pb = (const u32x4*)(qcodes + (size_t)r1 * 8);
    u32x4 x0 = pa[0], x1 = pa[1];
    u32x4 y0 = pb[0], y1 = pb[1];
    uint32_t aw[8] = {x0.x, x0.y, x0.z, x0.w, x1.x, x1.y, x1.z, x1.w};
    uint32_t bw[8] = {y0.x, y0.y, y0.z, y0.w, y1.x, y1.y, y1.z, y1.w};

    float crA = 0.f, crB = 0.f;
    float lAa = 0.f, lAb = 0.f;
    float lBa = 0.f, lBb = 0.f;
#pragma unroll
    for (int wd = 0; wd < 8; ++wd) {
        uint32_t wa = aw[wd];
        uint32_t wb = bw[wd];
#pragma unroll
        for (int j = 0; j < 8; ++j) {
            int f = wd * 8 + j;
            f32x4 c = coef[f];                       // uniform -> s_load
            float Af = (float)((wa >> (4 * j)) & 15u);
            float Bf = (float)((wb >> (4 * j)) & 15u);
            float pf = Af * Bf;                      // exact, <= 225
            if (wd < 4) {
                crA = fmaf(pf, c.x, crA);
                lAa = fmaf(Af, c.y, lAa);
                lBa = fmaf(Bf, c.z, lBa);
            } else {
                crB = fmaf(pf, c.x, crB);
                lAb = fmaf(Af, c.y, lAb);
                lBb = fmaf(Bf, c.z, lBb);
            }
        }
    }

    const float* cs = (const float*)coef;
    float Ca = cs[NF * 4 + 0];
    float Cb = cs[NF * 4 + 1];
    float es = expf(scale[0]);
    float bi = bias[0];
    float asum = crA + lAa + lBa + Ca;
    float bsum = crB + lAb + lBb + Cb;
    __builtin_nontemporal_store(asum * tanhf(bsum) * es + bi, out + n);
}

extern "C" void kernel_launch(void* const* d_in, const int* in_sizes, int n_in,
                              void* d_out, int out_size, void* d_ws, size_t ws_size,
                              hipStream_t stream) {
    const float* values = (const float*)d_in[0];  // [1,4,64]
    const float* feats  = (const float*)d_in[1];  // [100000,64]
    const float* scale  = (const float*)d_in[3];  // [1]
    const float* bias   = (const float*)d_in[4];  // [1]
    const int*   idx0   = (const int*)d_in[5];    // [N]
    const int*   idx1   = (const int*)d_in[6];    // [N]
    float*       out    = (float*)d_out;          // [N] f32

    uint32_t* qcodes = (uint32_t*)d_ws;                          // 3.2 MB
    float*    coef   = (float*)((char*)d_ws + COEF_OFF_BYTES);   // 64*4+2 floats

    int nwords = SROWS * 8;                       // 800000 = 3125 * 256 exact
    quantize_kernel<<<nwords / TPB, TPB, 0, stream>>>(feats, values, qcodes, coef);

    int N = out_size;
    query_kernel<<<(N + TPB - 1) / TPB, TPB, 0, stream>>>(
        qcodes, (const f32x4*)coef, scale, bias, idx0, idx1, out, N);
}